// Round 5
// baseline (180.557 us; speedup 1.0000x reference)
//
#include <hip/hip_runtime.h>
#include <stdint.h>

// Problem constants (from reference: B=2048, D=512, TAU=0.5)
#define DIM       512
#define NROWS     8192      // 4*B
#define HALF_ROWS 4096      // 2*B
#define TILE      128
#define NTILE     64        // NROWS / TILE
#define NBLK      2080      // live upper-triangle tile pairs (finalize counter)

typedef float  floatx4 __attribute__((ext_vector_type(4)));
typedef __bf16 bf16x8  __attribute__((ext_vector_type(8)));

// rep is stored in MFMA-fragment-native tiled layout:
//   page(R, kc) = 1 KB holding rows [16R,16R+16) x cols [32kc, 32kc+32)
//   within page, slot s (16 B) holds row (16R + (s&15)), cols 32kc+8*(s>>4)..+8
// so a wave's fragment load is rep + (R*16+kc)*512 + lane*8 shorts -> one
// fully-coalesced global_load_dwordx4 (lane i at base + 16 B * i).

// L2-normalize rows of [emb_i; emb_j] -> bf16 tiled rep; block 0 zeroes ws.
__global__ __launch_bounds__(256) void normalize_kernel(
    const float* __restrict__ emb_i, const float* __restrict__ emb_j,
    unsigned short* __restrict__ rep, double* __restrict__ ws)
{
    if (blockIdx.x == 0 && threadIdx.x == 0) {
        ws[0] = 0.0;
        ws[1] = 0.0;
        *(unsigned int*)((char*)ws + 16) = 0u;
    }
    const int wave = threadIdx.x >> 6;
    const int lane = threadIdx.x & 63;
    const int row  = blockIdx.x * 4 + wave;
    const float* src = (row < HALF_ROWS) ? (emb_i + (size_t)row * DIM)
                                         : (emb_j + (size_t)(row - HALF_ROWS) * DIM);
    const int c = lane * 8;
    float4 v0 = *(const float4*)(src + c);
    float4 v1 = *(const float4*)(src + c + 4);
    float s = v0.x*v0.x + v0.y*v0.y + v0.z*v0.z + v0.w*v0.w
            + v1.x*v1.x + v1.y*v1.y + v1.z*v1.z + v1.w*v1.w;
    #pragma unroll
    for (int off = 32; off; off >>= 1) s += __shfl_xor(s, off, 64);
    const float nrm = sqrtf(s);
    const float inv = 1.0f / fmaxf(nrm, 1e-12f);
    float f[8] = {v0.x*inv, v0.y*inv, v0.z*inv, v0.w*inv,
                  v1.x*inv, v1.y*inv, v1.z*inv, v1.w*inv};
    union { unsigned short h[8]; uint4 u; } pk;
    #pragma unroll
    for (int t = 0; t < 8; ++t) {   // fp32 -> bf16 round-to-nearest-even
        uint32_t b = __float_as_uint(f[t]);
        b += 0x7FFFu + ((b >> 16) & 1u);
        pk.h[t] = (unsigned short)(b >> 16);
    }
    // tiled store: this lane's 8 cols live in page (row>>4, lane>>2), slot
    // (lane&3)*16 + (row&15)
    const size_t pg = (size_t)((row >> 4) * 16 + (lane >> 2)) * 512;
    *(uint4*)(rep + pg + ((lane & 3) * 16 + (row & 15)) * 8) = pk.u;
}

// Fused Gram-tile + exp + reduction over upper-triangle tile pairs.
// Grid: 36 supertiles (8x8 tiles) x 64 blocks -> per-XCD working set ~2 MB.
// NO LDS staging, NO K-loop barriers: each wave computes its 64x64 quadrant
// independently, loading fragments straight global->VGPR (perfectly coalesced
// via the tiled rep layout) with a 2-set register pipeline. The barrier
// vmcnt(0) drain that capped rounds 1-4 is gone by construction.
__global__ __launch_bounds__(256, 3) void gram_kernel(
    const unsigned short* __restrict__ rep, double* __restrict__ ws,
    float* __restrict__ out)
{
    // supertile decode: 8x8 supertile upper triangle, row-major
    int s = blockIdx.x >> 6;
    int Bi = 0, rem = s;
    while (rem >= 8 - Bi) { rem -= 8 - Bi; ++Bi; }
    const int Bj = Bi + rem;
    const int t = blockIdx.x & 63;
    const int bi = Bi * 8 + (t >> 3);
    const int bj = Bj * 8 + (t & 7);
    if (bi > bj) return;   // dead only inside diagonal supertiles

    __shared__ float red[8];

    const int tid  = threadIdx.x;
    const int wave = tid >> 6, lane = tid & 63;
    const int wm = wave >> 1, wn = wave & 1;   // 2x2 waves of 64x64 quadrants
    const int m = lane & 15, quad = lane >> 4; // MFMA C/D fragment coords

    floatx4 acc[4][4];
    #pragma unroll
    for (int a = 0; a < 4; ++a)
        #pragma unroll
        for (int b = 0; b < 4; ++b)
            #pragma unroll
            for (int e = 0; e < 4; ++e) acc[a][b][e] = 0.0f;

    const int i0 = bi * TILE, j0 = bj * TILE;

    // fragment base pointers (R = 16-row group index, 8192 shorts per R step,
    // 512 shorts per kc step)
    const unsigned short* aP = rep + (size_t)((i0 >> 4) + wm * 4) * 8192 + lane * 8;
    const unsigned short* bP = rep + (size_t)((j0 >> 4) + wn * 4) * 8192 + lane * 8;

    bf16x8 a0[4], b0[4], a1[4], b1[4];
    #pragma unroll
    for (int mt = 0; mt < 4; ++mt) {
        a0[mt] = *(const bf16x8*)(aP + mt * 8192);
        b0[mt] = *(const bf16x8*)(bP + mt * 8192);
    }

    #pragma unroll 1
    for (int kc = 0; kc < 16; kc += 2) {
        const int k1 = kc + 1;
        const int k2 = (kc + 2 < 16) ? kc + 2 : 15;  // last iter: redundant (L1 hit)
        #pragma unroll
        for (int mt = 0; mt < 4; ++mt) {
            a1[mt] = *(const bf16x8*)(aP + k1 * 512 + mt * 8192);
            b1[mt] = *(const bf16x8*)(bP + k1 * 512 + mt * 8192);
        }
        #pragma unroll
        for (int mt = 0; mt < 4; ++mt)
            #pragma unroll
            for (int nt = 0; nt < 4; ++nt)
                acc[mt][nt] = __builtin_amdgcn_mfma_f32_16x16x32_bf16(
                    a0[mt], b0[nt], acc[mt][nt], 0, 0, 0);
        #pragma unroll
        for (int mt = 0; mt < 4; ++mt) {
            a0[mt] = *(const bf16x8*)(aP + k2 * 512 + mt * 8192);
            b0[mt] = *(const bf16x8*)(bP + k2 * 512 + mt * 8192);
        }
        #pragma unroll
        for (int mt = 0; mt < 4; ++mt)
            #pragma unroll
            for (int nt = 0; nt < 4; ++nt)
                acc[mt][nt] = __builtin_amdgcn_mfma_f32_16x16x32_bf16(
                    a1[mt], b1[nt], acc[mt][nt], 0, 0, 0);
    }

    // Epilogue: exp(sim/tau) = exp2(sim * 2/ln2); accumulate total + band sums.
    float s_all = 0.0f, s_pos = 0.0f;
    const float LOG2E2 = 2.885390081777927f;  // 2 / ln(2)
    #pragma unroll
    for (int mt = 0; mt < 4; ++mt) {
        const int ibase = i0 + wm * 64 + mt * 16 + quad * 4;
        #pragma unroll
        for (int nt = 0; nt < 4; ++nt) {
            const int j = j0 + wn * 64 + nt * 16 + m;
            const floatx4 a = acc[mt][nt];
            #pragma unroll
            for (int r2 = 0; r2 < 4; ++r2) {
                const int i = ibase + r2;
                const float e = exp2f(a[r2] * LOG2E2);
                if (i != j) s_all += e;
                const int d = j - i;  // upper triangle: band offsets positive
                if (d == 2048 || d == 4096 || d == 6144) s_pos += e;
            }
        }
    }
    #pragma unroll
    for (int off = 32; off; off >>= 1) {
        s_all += __shfl_xor(s_all, off, 64);
        s_pos += __shfl_xor(s_pos, off, 64);
    }
    if (lane == 0) { red[wave] = s_all; red[4 + wave] = s_pos; }
    __syncthreads();
    if (tid == 0) {
        const float w  = (bi == bj) ? 1.0f : 2.0f;
        const double ta = (double)((red[0] + red[1] + red[2] + red[3]) * w);
        const double tp = (double)((red[4] + red[5] + red[6] + red[7]) * w);
        // Device-scope atomics RMW at the coherent point. Order the counter
        // increment AFTER the sum-adds via a data dependency on their return
        // values -- no cache-invalidating __threadfence.
        const double r0 = atomicAdd(&ws[0], ta);
        const double r1 = atomicAdd(&ws[1], tp);
        const unsigned dep =
            (unsigned)(((unsigned long long)__double_as_longlong(r0) >> 63) &
                       ((unsigned long long)__double_as_longlong(r1) >> 63));
        unsigned int* cnt = (unsigned int*)((char*)ws + 16);
        const unsigned int prev = atomicAdd(cnt, 1u + dep);
        if (prev == NBLK - 1) {                 // last live block: fused finalize
            const double tot = atomicAdd(&ws[0], 0.0);  // coherent readback
            const double nom = atomicAdd(&ws[1], 0.0);
            const double den = tot - nom;
            out[0] = (float)(-log(nom / den) / (double)NROWS);
        }
    }
}

extern "C" void kernel_launch(void* const* d_in, const int* in_sizes, int n_in,
                              void* d_out, int out_size, void* d_ws, size_t ws_size,
                              hipStream_t stream) {
    const float* emb_i = (const float*)d_in[0];
    const float* emb_j = (const float*)d_in[1];
    float* out = (float*)d_out;
    double* ws = (double*)d_ws;                                   // accumulators + counter
    unsigned short* rep = (unsigned short*)((char*)d_ws + 256);   // bf16 tiled [8192][512]

    hipLaunchKernelGGL(normalize_kernel, dim3(NROWS / 4), dim3(256), 0, stream,
                       emb_i, emb_j, rep, ws);
    hipLaunchKernelGGL(gram_kernel, dim3(36 * 64), dim3(256), 0, stream, rep, ws, out);
}

// Round 6
// 159.607 us; speedup vs baseline: 1.1313x; 1.1313x over previous
//
#include <hip/hip_runtime.h>
#include <stdint.h>

// Problem constants (from reference: B=2048, D=512, TAU=0.5)
#define DIM       512
#define NROWS     8192      // 4*B
#define HALF_ROWS 4096      // 2*B
#define TILE      128
#define NTILE     64        // NROWS / TILE
#define NBLK      2080      // live upper-triangle tile pairs (finalize counter)

typedef float  floatx4 __attribute__((ext_vector_type(4)));
typedef __bf16 bf16x8  __attribute__((ext_vector_type(8)));

// rep tiled layout: page(R, kc) = 1 KB = rows [16R,16R+16) x cols [32kc,32kc+32)
//   page id = R*16 + kc, byte addr = id*1024
//   slot s (16 B): row 16R + (s&15), col octet (s>>4)  -> matches the MFMA
//   A/B operand layout (m = lane&15, k = quad*8 + j) at slot = lane.

__device__ __forceinline__ void async_copy16(const unsigned short* g, unsigned short* l) {
    __builtin_amdgcn_global_load_lds(
        (const __attribute__((address_space(1))) uint32_t*)(g),
        (__attribute__((address_space(3))) uint32_t*)(l),
        16, 0, 0);
}

// L2-normalize rows of [emb_i; emb_j] -> bf16 tiled rep; block 0 zeroes ws.
__global__ __launch_bounds__(256) void normalize_kernel(
    const float* __restrict__ emb_i, const float* __restrict__ emb_j,
    unsigned short* __restrict__ rep, double* __restrict__ ws)
{
    if (blockIdx.x == 0 && threadIdx.x == 0) {
        ws[0] = 0.0;
        ws[1] = 0.0;
        *(unsigned int*)((char*)ws + 16) = 0u;
    }
    const int wave = threadIdx.x >> 6;
    const int lane = threadIdx.x & 63;
    const int row  = blockIdx.x * 4 + wave;
    const float* src = (row < HALF_ROWS) ? (emb_i + (size_t)row * DIM)
                                         : (emb_j + (size_t)(row - HALF_ROWS) * DIM);
    const int c = lane * 8;
    float4 v0 = *(const float4*)(src + c);
    float4 v1 = *(const float4*)(src + c + 4);
    float s = v0.x*v0.x + v0.y*v0.y + v0.z*v0.z + v0.w*v0.w
            + v1.x*v1.x + v1.y*v1.y + v1.z*v1.z + v1.w*v1.w;
    #pragma unroll
    for (int off = 32; off; off >>= 1) s += __shfl_xor(s, off, 64);
    const float nrm = sqrtf(s);
    const float inv = 1.0f / fmaxf(nrm, 1e-12f);
    float f[8] = {v0.x*inv, v0.y*inv, v0.z*inv, v0.w*inv,
                  v1.x*inv, v1.y*inv, v1.z*inv, v1.w*inv};
    union { unsigned short h[8]; uint4 u; } pk;
    #pragma unroll
    for (int t = 0; t < 8; ++t) {   // fp32 -> bf16 round-to-nearest-even
        uint32_t b = __float_as_uint(f[t]);
        b += 0x7FFFu + ((b >> 16) & 1u);
        pk.h[t] = (unsigned short)(b >> 16);
    }
    // tiled store: lane's 8 cols -> page (row>>4, lane>>2), slot (lane&3)*16+(row&15)
    const size_t pg = (size_t)((row >> 4) * 16 + (lane >> 2)) * 512;
    *(uint4*)(rep + pg + ((lane & 3) * 16 + (row & 15)) * 8) = pk.u;
}

// Fused Gram-tile + exp + reduction over upper-triangle tile pairs.
// Union of measured wins: m97 2-barrier BK32 LDS structure (r1, best) +
// supertile L2 locality (r3/r4) + no __threadfence (r4) + tiled rep layout
// making DMA staging page-linear and ds_read_b128 conflict-free (no swizzle).
__global__ __launch_bounds__(256, 3) void gram_kernel(
    const unsigned short* __restrict__ rep, double* __restrict__ ws,
    float* __restrict__ out)
{
    // supertile decode: 8x8 supertile upper triangle, row-major
    int s = blockIdx.x >> 6;
    int Bi = 0, rem = s;
    while (rem >= 8 - Bi) { rem -= 8 - Bi; ++Bi; }
    const int Bj = Bi + rem;
    const int t = blockIdx.x & 63;
    const int bi = Bi * 8 + (t >> 3);
    const int bj = Bj * 8 + (t & 7);
    if (bi > bj) return;   // dead only inside diagonal supertiles

    __shared__ unsigned short As[TILE * 32];   // 8 KB = 8 pages (A tile, one kc)
    __shared__ unsigned short Bs[TILE * 32];   // 8 KB
    __shared__ float red[8];

    const int tid  = threadIdx.x;
    const int wave = tid >> 6, lane = tid & 63;
    const int wm = wave >> 1, wn = wave & 1;   // 2x2 waves of 64x64 quadrants
    const int m = lane & 15, quad = lane >> 4; // MFMA C/D fragment coords

    floatx4 acc[4][4];
    #pragma unroll
    for (int a = 0; a < 4; ++a)
        #pragma unroll
        for (int b = 0; b < 4; ++b)
            #pragma unroll
            for (int e = 0; e < 4; ++e) acc[a][b][e] = 0.0f;

    // staging addresses (page-linear; wave-uniform base + lane*16 by construction)
    // chunk q*256+tid -> page rp = q*4+wave, element (lane)*8 within page
    const int i0 = bi * TILE, j0 = bj * TILE;
    // page id for A tile, kc phase: bi*128 + 16*rp + kc  (byte addr = id*1024)
    const unsigned short* aSrc0 = rep + ((size_t)(bi * 128 + 16 * (0 * 4 + wave))) * 512 + lane * 8;
    const unsigned short* aSrc1 = rep + ((size_t)(bi * 128 + 16 * (1 * 4 + wave))) * 512 + lane * 8;
    const unsigned short* bSrc0 = rep + ((size_t)(bj * 128 + 16 * (0 * 4 + wave))) * 512 + lane * 8;
    const unsigned short* bSrc1 = rep + ((size_t)(bj * 128 + 16 * (1 * 4 + wave))) * 512 + lane * 8;
    unsigned short* aDst0 = As + (size_t)(0 * 256 + tid) * 8;
    unsigned short* aDst1 = As + (size_t)(1 * 256 + tid) * 8;
    unsigned short* bDst0 = Bs + (size_t)(0 * 256 + tid) * 8;
    unsigned short* bDst1 = Bs + (size_t)(1 * 256 + tid) * 8;

    // LDS fragment pointers (page p at p*512 shorts; slot = lane)
    const unsigned short* aFrag = As + (size_t)(wm * 4) * 512 + lane * 8;
    const unsigned short* bFrag = Bs + (size_t)(wn * 4) * 512 + lane * 8;

    for (int kc = 0; kc < 16; ++kc) {
        async_copy16(aSrc0 + kc * 512, aDst0);
        async_copy16(bSrc0 + kc * 512, bDst0);
        async_copy16(aSrc1 + kc * 512, aDst1);
        async_copy16(bSrc1 + kc * 512, bDst1);
        __syncthreads();   // drain DMAs + rendezvous

        bf16x8 af[4], bfr[4];
        #pragma unroll
        for (int mt = 0; mt < 4; ++mt) {
            af[mt]  = *(const bf16x8*)(aFrag + mt * 512);
            bfr[mt] = *(const bf16x8*)(bFrag + mt * 512);
        }
        #pragma unroll
        for (int mt = 0; mt < 4; ++mt)
            #pragma unroll
            for (int nt = 0; nt < 4; ++nt)
                acc[mt][nt] = __builtin_amdgcn_mfma_f32_16x16x32_bf16(
                    af[mt], bfr[nt], acc[mt][nt], 0, 0, 0);
        __syncthreads();   // protect LDS before next phase overwrites
    }

    // Epilogue: exp(sim/tau) = exp2(sim * 2/ln2); accumulate total + band sums.
    float s_all = 0.0f, s_pos = 0.0f;
    const float LOG2E2 = 2.885390081777927f;  // 2 / ln(2)
    #pragma unroll
    for (int mt = 0; mt < 4; ++mt) {
        const int ibase = i0 + wm * 64 + mt * 16 + quad * 4;
        #pragma unroll
        for (int nt = 0; nt < 4; ++nt) {
            const int j = j0 + wn * 64 + nt * 16 + m;
            const floatx4 a = acc[mt][nt];
            #pragma unroll
            for (int r2 = 0; r2 < 4; ++r2) {
                const int i = ibase + r2;
                const float e = exp2f(a[r2] * LOG2E2);
                if (i != j) s_all += e;
                const int d = j - i;  // upper triangle: band offsets positive
                if (d == 2048 || d == 4096 || d == 6144) s_pos += e;
            }
        }
    }
    #pragma unroll
    for (int off = 32; off; off >>= 1) {
        s_all += __shfl_xor(s_all, off, 64);
        s_pos += __shfl_xor(s_pos, off, 64);
    }
    if (lane == 0) { red[wave] = s_all; red[4 + wave] = s_pos; }
    __syncthreads();
    if (tid == 0) {
        const float w  = (bi == bj) ? 1.0f : 2.0f;
        const double ta = (double)((red[0] + red[1] + red[2] + red[3]) * w);
        const double tp = (double)((red[4] + red[5] + red[6] + red[7]) * w);
        // Device-scope atomics RMW at the coherent point. Order the counter
        // increment AFTER the sum-adds via a data dependency on their return
        // values -- no cache-invalidating __threadfence.
        const double r0 = atomicAdd(&ws[0], ta);
        const double r1 = atomicAdd(&ws[1], tp);
        const unsigned dep =
            (unsigned)(((unsigned long long)__double_as_longlong(r0) >> 63) &
                       ((unsigned long long)__double_as_longlong(r1) >> 63));
        unsigned int* cnt = (unsigned int*)((char*)ws + 16);
        const unsigned int prev = atomicAdd(cnt, 1u + dep);
        if (prev == NBLK - 1) {                 // last live block: fused finalize
            const double tot = atomicAdd(&ws[0], 0.0);  // coherent readback
            const double nom = atomicAdd(&ws[1], 0.0);
            const double den = tot - nom;
            out[0] = (float)(-log(nom / den) / (double)NROWS);
        }
    }
}

extern "C" void kernel_launch(void* const* d_in, const int* in_sizes, int n_in,
                              void* d_out, int out_size, void* d_ws, size_t ws_size,
                              hipStream_t stream) {
    const float* emb_i = (const float*)d_in[0];
    const float* emb_j = (const float*)d_in[1];
    float* out = (float*)d_out;
    double* ws = (double*)d_ws;                                   // accumulators + counter
    unsigned short* rep = (unsigned short*)((char*)d_ws + 256);   // bf16 tiled [8192][512]

    hipLaunchKernelGGL(normalize_kernel, dim3(NROWS / 4), dim3(256), 0, stream,
                       emb_i, emb_j, rep, ws);
    hipLaunchKernelGGL(gram_kernel, dim3(36 * 64), dim3(256), 0, stream, rep, ws, out);
}